// Round 9
// baseline (267.410 us; speedup 1.0000x reference)
//
#include <hip/hip_runtime.h>
#include <stdint.h>

// Binarized 5-layer MLP, B=32768, dims 784->256->256->256->256->10.
// 7 dispatches (dataflow minimum-ish: each BN needs grid-wide stats of the
// previous matmul; kernel boundary = cheapest grid barrier).
// Matmuls as XOR+popcount on packed sign bits: h = in_n - 2*d.
// BN stats = exact integer sums of d per column into 16 replicated atomic
// slots; consumers reduce replicas. binarize(BN(h)) == (A*d + C >= 0),
// A = -2*g*s, C = 2*g*s*mean_d + b, s = rsqrt(4*(E[d^2]-E[d]^2)+eps).
// Round 9: round-4 profile showed mm0 VGPR_Count=32 -- impossible with
// w0r[13] (26 VGPRs) resident => compiler SANK the weight loads into the
// row loop (13 dependent L2 re-loads x 32 iters = the mystery 40us stall,
// VALUBusy 28%, HBM 16%). Fix: launch_bounds with VGPR headroom, named
// scalar weight registers, partial unroll so full-unroll pressure never
// triggers the sinking heuristic.

typedef unsigned long long u64;

#define NREP 16

// ---- workspace layout (bytes) ----
#define OFF_WB0   0u          // u64 [16][256] = 32768 (words 0..12 used)
#define OFF_WB1   32768u      // u64 [4][256] = 8192
#define OFF_WB2   40960u
#define OFF_WB3   49152u
#define OFF_WB4   57344u      // u64 [4][16] = 512 (10 cols used)
#define OFF_SUMD  57856u      // int32 [16][5][256] = 81920
#define OFF_SUMDD 139776u     // u64   [16][5][256] = 163840
#define STATS_INT4 15360      // (81920+163840)/16
#define OFF_A0    (1u<<20)    // u64 [32768][16] = 4 MiB
#define OFF_A1    (6u<<20)    // u64 [32768][4] = 1 MiB each
#define OFF_A2    (7u<<20)
#define OFF_A3    (8u<<20)
#define OFF_A4    (9u<<20)
#define OFF_H0    (10u<<20)   // short [32768][256] = 16 MiB

// 784-elem row -> 13 packed u64 words (consistent permuted bit order).
// Returns word[lane] for lane<13, 0 for lane 13..63.
__device__ __forceinline__ u64 pack784_sel(const float* __restrict__ src,
                                           float thr, int lane) {
  u64 w[13];
  const float4* s4 = (const float4*)src;
#pragma unroll
  for (int j = 0; j < 3; ++j) {
    float4 v = s4[j * 64 + lane];
    w[4*j+0] = __ballot(v.x >= thr);
    w[4*j+1] = __ballot(v.y >= thr);
    w[4*j+2] = __ballot(v.z >= thr);
    w[4*j+3] = __ballot(v.w >= thr);
  }
  float4 v = make_float4(-1.f, -1.f, -1.f, -1.f);
  if (lane < 4) v = s4[192 + lane];
  u64 m0 = __ballot(v.x >= thr) & 0xFull;
  u64 m1 = __ballot(v.y >= thr) & 0xFull;
  u64 m2 = __ballot(v.z >= thr) & 0xFull;
  u64 m3 = __ballot(v.w >= thr) & 0xFull;
  w[12] = m0 | (m1 << 4) | (m2 << 8) | (m3 << 12);
  u64 sel = 0;
#pragma unroll
  for (int i = 0; i < 13; ++i) sel = (lane == i) ? w[i] : sel;
  return sel;
}

// 256-elem row -> 4 packed u64 words; bit l of word j <-> element 64*j+l.
__device__ __forceinline__ u64 pack256_sel(const float* __restrict__ src, int lane) {
  u64 w[4];
#pragma unroll
  for (int j = 0; j < 4; ++j) w[j] = __ballot(src[j * 64 + lane] >= 0.0f);
  u64 sel = 0;
#pragma unroll
  for (int i = 0; i < 4; ++i) sel = (lane == i) ? w[i] : sel;
  return sel;
}

// Reduce the 16 stats replicas for (layer, col); gs = g*rsqrt(var+eps), mean_d.
__device__ __forceinline__ void bn_gs_md(const int* __restrict__ sumd_rep,
                                         const u64* __restrict__ sumdd_rep,
                                         int layer, int col,
                                         const float* __restrict__ g,
                                         float& gs, float& md_out) {
  long long sd = 0; u64 sdd = 0;
#pragma unroll
  for (int r = 0; r < NREP; ++r) {
    sd  += sumd_rep [(r * 5 + layer) * 256 + col];
    sdd += sumdd_rep[(r * 5 + layer) * 256 + col];
  }
  double md  = (double)sd  * (1.0 / 32768.0);
  double mdd = (double)sdd * (1.0 / 32768.0);
  float var = (float)(4.0 * (mdd - md * md));
  float s   = rsqrtf(var + 1e-5f);
  gs = g[col] * s;
  md_out = (float)md;
}

// ---------------- K1: pack x -> a0 bits + all weights + zero stats ----------------
__global__ __launch_bounds__(256) void xpack_all(
    const float* __restrict__ x,
    const float* __restrict__ W0, const float* __restrict__ W1,
    const float* __restrict__ W2, const float* __restrict__ W3,
    const float* __restrict__ W4,
    u64* __restrict__ a0,
    u64* __restrict__ wb0, u64* __restrict__ wb1, u64* __restrict__ wb2,
    u64* __restrict__ wb3, u64* __restrict__ wb4, int4* __restrict__ statsZ) {
  const int b = blockIdx.x, tid = threadIdx.x;
  const int lane = tid & 63, wave = tid >> 6;
  int gid = b * 256 + tid;
  if (gid < STATS_INT4) statsZ[gid] = make_int4(0, 0, 0, 0);
  if (b < 2048) {
    const int row0 = b * 16 + wave * 4;              // 4 consecutive rows per wave
    __shared__ u64 st[4 * 64];
    const float* base = x + (size_t)row0 * 784;
#pragma unroll
    for (int it = 0; it < 4; ++it) {
      u64 sel = pack784_sel(base + it * 784, 0.5f, lane);
      if (lane < 16) st[wave * 64 + it * 16 + lane] = sel;   // words 13..15 = 0
    }
    a0[(size_t)row0 * 16 + lane] = st[wave * 64 + lane];     // full-wave 512B store
  } else if (b < 2112) {
    int row = (b - 2048) * 4 + wave;
    u64 sel = pack784_sel(W0 + (size_t)row * 784, 0.0f, lane);
    if (lane < 13) wb0[lane * 256 + row] = sel;
  } else if (b < 2176) {
    int row = (b - 2112) * 4 + wave;
    u64 sel = pack256_sel(W1 + (size_t)row * 256, lane);
    if (lane < 4) wb1[lane * 256 + row] = sel;
  } else if (b < 2240) {
    int row = (b - 2176) * 4 + wave;
    u64 sel = pack256_sel(W2 + (size_t)row * 256, lane);
    if (lane < 4) wb2[lane * 256 + row] = sel;
  } else if (b < 2304) {
    int row = (b - 2240) * 4 + wave;
    u64 sel = pack256_sel(W3 + (size_t)row * 256, lane);
    if (lane < 4) wb3[lane * 256 + row] = sel;
  } else {
    for (int row = wave; row < 10; row += 4) {
      u64 sel = pack256_sel(W4 + (size_t)row * 256, lane);
      if (lane < 4) wb4[lane * 16 + row] = sel;
    }
  }
}

// ---------------- K2: layer-0 matmul from a0 bits, h0 + stats0 ----------------
// (256,2): 256-VGPR cap so the 13 weight words STAY in registers; named
// scalars (no array) + partial unroll to avoid the sinking heuristic.
__global__ __launch_bounds__(256, 2) void mm0_kernel(
    const u64* __restrict__ a0, const u64* __restrict__ wb0T,
    short* __restrict__ h0, int* __restrict__ sumd_rep, u64* __restrict__ sumdd_rep) {
  const int b = blockIdx.x, tid = threadIdx.x;
  const int row0 = b * 32;
  __shared__ u64 a0T[32 * 16];                       // 4 KB tile
  a0T[tid]       = a0[(size_t)row0 * 16 + tid];      // coalesced 2KB
  a0T[256 + tid] = a0[(size_t)row0 * 16 + 256 + tid];
  const ulonglong2* wp = (const ulonglong2*)wb0T;    // [i*128 + tid/2]... load pairwise
  // 13 named weight registers, loaded once, kept live.
  u64 w0  = wb0T[ 0 * 256 + tid], w1  = wb0T[ 1 * 256 + tid];
  u64 w2  = wb0T[ 2 * 256 + tid], w3  = wb0T[ 3 * 256 + tid];
  u64 w4  = wb0T[ 4 * 256 + tid], w5  = wb0T[ 5 * 256 + tid];
  u64 w6  = wb0T[ 6 * 256 + tid], w7  = wb0T[ 7 * 256 + tid];
  u64 w8  = wb0T[ 8 * 256 + tid], w9  = wb0T[ 9 * 256 + tid];
  u64 w10 = wb0T[10 * 256 + tid], w11 = wb0T[11 * 256 + tid];
  u64 w12 = wb0T[12 * 256 + tid];
  (void)wp;
  __syncthreads();
  int sd = 0; unsigned sdd = 0;                      // 32*784^2 = 19.7M fits u32
#pragma unroll 4
  for (int r = 0; r < 32; ++r) {
    const u64* ap = &a0T[r * 16];
    int d = __popcll(ap[0] ^ w0)  + __popcll(ap[1] ^ w1)
          + __popcll(ap[2] ^ w2)  + __popcll(ap[3] ^ w3)
          + __popcll(ap[4] ^ w4)  + __popcll(ap[5] ^ w5)
          + __popcll(ap[6] ^ w6)  + __popcll(ap[7] ^ w7)
          + __popcll(ap[8] ^ w8)  + __popcll(ap[9] ^ w9)
          + __popcll(ap[10] ^ w10) + __popcll(ap[11] ^ w11)
          + __popcll(ap[12] ^ w12);
    h0[(size_t)(row0 + r) * 256 + tid] = (short)(784 - 2 * d);
    sd += d; sdd += (unsigned)(d * d);
  }
  const int rep = b & (NREP - 1);
  atomicAdd(&sumd_rep [(rep * 5 + 0) * 256 + tid], sd);
  atomicAdd(&sumdd_rep[(rep * 5 + 0) * 256 + tid], (u64)sdd);
}

// ---------------- K3: binarize BN(h0) -> a1 bits, + layer-1 stats ----------------
__global__ __launch_bounds__(256, 4) void b0_kernel(
    const short* __restrict__ h0,
    int* __restrict__ sumd_rep, u64* __restrict__ sumdd_rep,
    const float* __restrict__ g0, const float* __restrict__ bb0,
    u64* __restrict__ a1, const u64* __restrict__ wb1T) {
  const int b = blockIdx.x, tid = threadIdx.x;
  const int lane = tid & 63, wave = tid >> 6;
  const int row0 = b * 32;
  float gs, md;
  bn_gs_md(sumd_rep, sumdd_rep, 0, tid, g0, gs, md);
  const float mh = 784.0f - 2.0f * md;
  const float bb = bb0[tid];
  u64 wn0 = wb1T[0 * 256 + tid], wn1 = wb1T[1 * 256 + tid];
  u64 wn2 = wb1T[2 * 256 + tid], wn3 = wb1T[3 * 256 + tid];
  __shared__ u64 bits[32 * 4];
#pragma unroll 8
  for (int r = 0; r < 32; ++r) {
    float hv = (float)h0[(size_t)(row0 + r) * 256 + tid];
    bool bit = fmaf(gs, hv - mh, bb) >= 0.0f;
    u64 m = __ballot(bit);
    if (lane == 0) bits[r * 4 + wave] = m;
  }
  __syncthreads();
  if (tid < 128) a1[(size_t)row0 * 4 + tid] = bits[tid];
  int sd = 0; unsigned sdd = 0;     // 32 * 256^2 = 2.1M fits u32
#pragma unroll 8
  for (int r = 0; r < 32; ++r) {
    int d = __popcll(bits[r*4+0] ^ wn0) + __popcll(bits[r*4+1] ^ wn1)
          + __popcll(bits[r*4+2] ^ wn2) + __popcll(bits[r*4+3] ^ wn3);
    sd += d; sdd += (unsigned)(d * d);
  }
  const int rep = b & (NREP - 1);
  atomicAdd(&sumd_rep [(rep * 5 + 1) * 256 + tid], sd);
  atomicAdd(&sumdd_rep[(rep * 5 + 1) * 256 + tid], (u64)sdd);
}

// ---------------- K4..K6: layer k -> a_{k+1} bits + layer-(k+1) stats ----------------
template<int LAYER, int NNEXT, int NSTRIDE>
__global__ __launch_bounds__(256, 4) void bmid_kernel(
    const u64* __restrict__ aK, const u64* __restrict__ wbKT,
    int* __restrict__ sumd_rep, u64* __restrict__ sumdd_rep,
    const float* __restrict__ gK, const float* __restrict__ bK,
    u64* __restrict__ aN, const u64* __restrict__ wbNT) {
  const int b = blockIdx.x, tid = threadIdx.x;
  const int lane = tid & 63, wave = tid >> 6;
  const int row0 = b * 32;
  __shared__ u64 ain[32 * 4];
  __shared__ u64 bits[32 * 4];
  if (tid < 128) ain[tid] = aK[(size_t)row0 * 4 + tid];
  float gs, md;
  bn_gs_md(sumd_rep, sumdd_rep, LAYER, tid, gK, gs, md);
  const float A = -2.0f * gs;
  const float C = fmaf(gs, 2.0f * md, bK[tid]);
  u64 wk0 = wbKT[0 * 256 + tid], wk1 = wbKT[1 * 256 + tid];
  u64 wk2 = wbKT[2 * 256 + tid], wk3 = wbKT[3 * 256 + tid];
  __syncthreads();
#pragma unroll 8
  for (int r = 0; r < 32; ++r) {
    int d = __popcll(ain[r*4+0] ^ wk0) + __popcll(ain[r*4+1] ^ wk1)
          + __popcll(ain[r*4+2] ^ wk2) + __popcll(ain[r*4+3] ^ wk3);
    bool bit = fmaf(A, (float)d, C) >= 0.0f;
    u64 m = __ballot(bit);
    if (lane == 0) bits[r * 4 + wave] = m;
  }
  __syncthreads();
  if (tid < 128) aN[(size_t)row0 * 4 + tid] = bits[tid];
  if (tid < NNEXT) {
    u64 wn0 = wbNT[0 * NSTRIDE + tid], wn1 = wbNT[1 * NSTRIDE + tid];
    u64 wn2 = wbNT[2 * NSTRIDE + tid], wn3 = wbNT[3 * NSTRIDE + tid];
    int sd = 0; unsigned sdd = 0;
#pragma unroll 8
    for (int r = 0; r < 32; ++r) {
      int d = __popcll(bits[r*4+0] ^ wn0) + __popcll(bits[r*4+1] ^ wn1)
            + __popcll(bits[r*4+2] ^ wn2) + __popcll(bits[r*4+3] ^ wn3);
      sd += d; sdd += (unsigned)(d * d);
    }
    const int rep = b & (NREP - 1);
    atomicAdd(&sumd_rep [(rep * 5 + LAYER + 1) * 256 + tid], sd);
    atomicAdd(&sumdd_rep[(rep * 5 + LAYER + 1) * 256 + tid], (u64)sdd);
  }
}

// ---------------- K7: layer 4 + BN + softmax ----------------
__global__ __launch_bounds__(256) void b4_kernel(
    const u64* __restrict__ a4, const u64* __restrict__ wb4T,
    const int* __restrict__ sumd_rep, const u64* __restrict__ sumdd_rep,
    const float* __restrict__ g4, const float* __restrict__ bb4,
    float* __restrict__ out) {
  __shared__ float sA[10], sC[10];
  __shared__ u64 w4s[40];
  const int tid = threadIdx.x;
  if (tid < 40) w4s[tid] = wb4T[(tid & 3) * 16 + (tid >> 2)];  // [c*4+i] = word i of class c
  if (tid < 10) {
    float gs, md;
    bn_gs_md(sumd_rep, sumdd_rep, 4, tid, g4, gs, md);
    sA[tid] = -2.0f * gs;
    sC[tid] = fmaf(gs, 2.0f * md, bb4[tid]);
  }
  __syncthreads();
  const int row = blockIdx.x * 256 + tid;
  u64 a[4];
#pragma unroll
  for (int i = 0; i < 4; ++i) a[i] = a4[(size_t)row * 4 + i];
  float y[10];
  float mx = -1e30f;
#pragma unroll
  for (int c = 0; c < 10; ++c) {
    int d = __popcll(a[0] ^ w4s[c*4+0]) + __popcll(a[1] ^ w4s[c*4+1])
          + __popcll(a[2] ^ w4s[c*4+2]) + __popcll(a[3] ^ w4s[c*4+3]);
    y[c] = fmaf(sA[c], (float)d, sC[c]);
    mx = fmaxf(mx, y[c]);
  }
  float sum = 0.0f;
#pragma unroll
  for (int c = 0; c < 10; ++c) { y[c] = __expf(y[c] - mx); sum += y[c]; }
  float inv = 1.0f / sum;
#pragma unroll
  for (int c = 0; c < 10; ++c) out[(size_t)row * 10 + c] = y[c] * inv;
}

// ---------------- host ----------------
extern "C" void kernel_launch(void* const* d_in, const int* in_sizes, int n_in,
                              void* d_out, int out_size, void* d_ws, size_t ws_size,
                              hipStream_t stream) {
  (void)in_sizes; (void)n_in; (void)out_size; (void)ws_size;
  const float* x   = (const float*)d_in[0];
  const float* W0  = (const float*)d_in[1];
  const float* g0  = (const float*)d_in[2];
  const float* bb0 = (const float*)d_in[3];
  const float* W1  = (const float*)d_in[4];
  const float* g1  = (const float*)d_in[5];
  const float* bb1 = (const float*)d_in[6];
  const float* W2  = (const float*)d_in[7];
  const float* g2  = (const float*)d_in[8];
  const float* bb2 = (const float*)d_in[9];
  const float* W3  = (const float*)d_in[10];
  const float* g3  = (const float*)d_in[11];
  const float* bb3 = (const float*)d_in[12];
  const float* W4  = (const float*)d_in[13];
  const float* g4  = (const float*)d_in[14];
  const float* bb4 = (const float*)d_in[15];

  char* ws = (char*)d_ws;
  u64*   wb0 = (u64*)(ws + OFF_WB0);
  u64*   wb1 = (u64*)(ws + OFF_WB1);
  u64*   wb2 = (u64*)(ws + OFF_WB2);
  u64*   wb3 = (u64*)(ws + OFF_WB3);
  u64*   wb4 = (u64*)(ws + OFF_WB4);
  int*   sumd  = (int*)(ws + OFF_SUMD);
  u64*   sumdd = (u64*)(ws + OFF_SUMDD);
  u64*   a0 = (u64*)(ws + OFF_A0);
  u64*   a1 = (u64*)(ws + OFF_A1);
  u64*   a2 = (u64*)(ws + OFF_A2);
  u64*   a3 = (u64*)(ws + OFF_A3);
  u64*   a4 = (u64*)(ws + OFF_A4);
  short* h0 = (short*)(ws + OFF_H0);

  xpack_all<<<2305, 256, 0, stream>>>(x, W0, W1, W2, W3, W4, a0,
                                      wb0, wb1, wb2, wb3, wb4,
                                      (int4*)(ws + OFF_SUMD));
  mm0_kernel<<<1024, 256, 0, stream>>>(a0, wb0, h0, sumd, sumdd);
  b0_kernel<<<1024, 256, 0, stream>>>(h0, sumd, sumdd, g0, bb0, a1, wb1);
  bmid_kernel<1, 256, 256><<<1024, 256, 0, stream>>>(a1, wb1, sumd, sumdd, g1, bb1, a2, wb2);
  bmid_kernel<2, 256, 256><<<1024, 256, 0, stream>>>(a2, wb2, sumd, sumdd, g2, bb2, a3, wb3);
  bmid_kernel<3, 10, 16><<<1024, 256, 0, stream>>>(a3, wb3, sumd, sumdd, g3, bb3, a4, wb4);
  b4_kernel<<<128, 256, 0, stream>>>(a4, wb4, sumd, sumdd, g4, bb4, (float*)d_out);
}

// Round 10
// 255.409 us; speedup vs baseline: 1.0470x; 1.0470x over previous
//
#include <hip/hip_runtime.h>
#include <stdint.h>

// Binarized 5-layer MLP, B=32768, dims 784->256->256->256->256->10.
// 7 dispatches (dataflow minimum: each BN needs grid-wide stats of the
// previous matmul; kernel boundary = cheapest grid barrier).
// Matmuls as XOR+popcount on packed sign bits: h = in_n - 2*d.
// BN stats = exact integer sums of d per column into 16 replicated atomic
// slots; consumers reduce replicas. binarize(BN(h)) == (A*d + C >= 0),
// A = -2*g*s, C = 2*g*s*mean_d + b, s = rsqrt(4*(E[d^2]-E[d]^2)+eps).
// Round 10: round-6 merged structure (pack x inside mm0; best total 257)
// + round-9 anti-sinking fixes it never got: named scalar weight regs,
// partial unroll, launch_bounds(256,3) (round-6's (256,8) = 64-VGPR cap
// forced weight-load sinking + ~2 pack loads in flight; round-4 profile
// showed VGPR_Count=32).

typedef unsigned long long u64;

#define NREP 16

// ---- workspace layout (bytes) ----
#define OFF_WB0   0u          // u64 [16][256] = 32768 (words 0..12 used)
#define OFF_WB1   32768u      // u64 [4][256] = 8192
#define OFF_WB2   40960u
#define OFF_WB3   49152u
#define OFF_WB4   57344u      // u64 [4][16] = 512 (10 cols used)
#define OFF_SUMD  57856u      // int32 [16][5][256] = 81920
#define OFF_SUMDD 139776u     // u64   [16][5][256] = 163840
#define STATS_INT4 15360      // (81920+163840)/16
#define OFF_A1    (1u<<20)    // u64 [32768][4] = 1 MiB each
#define OFF_A2    (2u<<20)
#define OFF_A3    (3u<<20)
#define OFF_A4    (4u<<20)
#define OFF_H0    (5u<<20)    // short [32768][256] = 16 MiB

// 784-elem row -> 13 packed u64 words (consistent permuted bit order).
// Returns word[lane] for lane<13, 0 for lane 13..63.
__device__ __forceinline__ u64 pack784_sel(const float* __restrict__ src,
                                           float thr, int lane) {
  u64 w[13];
  const float4* s4 = (const float4*)src;
#pragma unroll
  for (int j = 0; j < 3; ++j) {
    float4 v = s4[j * 64 + lane];
    w[4*j+0] = __ballot(v.x >= thr);
    w[4*j+1] = __ballot(v.y >= thr);
    w[4*j+2] = __ballot(v.z >= thr);
    w[4*j+3] = __ballot(v.w >= thr);
  }
  float4 v = make_float4(-1.f, -1.f, -1.f, -1.f);
  if (lane < 4) v = s4[192 + lane];
  u64 m0 = __ballot(v.x >= thr) & 0xFull;
  u64 m1 = __ballot(v.y >= thr) & 0xFull;
  u64 m2 = __ballot(v.z >= thr) & 0xFull;
  u64 m3 = __ballot(v.w >= thr) & 0xFull;
  w[12] = m0 | (m1 << 4) | (m2 << 8) | (m3 << 12);
  u64 sel = 0;
#pragma unroll
  for (int i = 0; i < 13; ++i) sel = (lane == i) ? w[i] : sel;
  return sel;
}

// 256-elem row -> 4 packed u64 words; bit l of word j <-> element 64*j+l.
__device__ __forceinline__ u64 pack256_sel(const float* __restrict__ src, int lane) {
  u64 w[4];
#pragma unroll
  for (int j = 0; j < 4; ++j) w[j] = __ballot(src[j * 64 + lane] >= 0.0f);
  u64 sel = 0;
#pragma unroll
  for (int i = 0; i < 4; ++i) sel = (lane == i) ? w[i] : sel;
  return sel;
}

// Reduce the 16 stats replicas for (layer, col); gs = g*rsqrt(var+eps), mean_d.
__device__ __forceinline__ void bn_gs_md(const int* __restrict__ sumd_rep,
                                         const u64* __restrict__ sumdd_rep,
                                         int layer, int col,
                                         const float* __restrict__ g,
                                         float& gs, float& md_out) {
  long long sd = 0; u64 sdd = 0;
#pragma unroll
  for (int r = 0; r < NREP; ++r) {
    sd  += sumd_rep [(r * 5 + layer) * 256 + col];
    sdd += sumdd_rep[(r * 5 + layer) * 256 + col];
  }
  double md  = (double)sd  * (1.0 / 32768.0);
  double mdd = (double)sdd * (1.0 / 32768.0);
  float var = (float)(4.0 * (mdd - md * md));
  float s   = rsqrtf(var + 1e-5f);
  gs = g[col] * s;
  md_out = (float)md;
}

// ---------------- K1: pack all weights (transposed) + zero stats ----------------
__global__ __launch_bounds__(256) void pack_weights(
    const float* __restrict__ W0, const float* __restrict__ W1,
    const float* __restrict__ W2, const float* __restrict__ W3,
    const float* __restrict__ W4,
    u64* __restrict__ wb0, u64* __restrict__ wb1, u64* __restrict__ wb2,
    u64* __restrict__ wb3, u64* __restrict__ wb4, int4* __restrict__ statsZ) {
  const int b = blockIdx.x, tid = threadIdx.x;
  const int lane = tid & 63, wave = tid >> 6;
  int gid = b * 256 + tid;
  if (gid < STATS_INT4) statsZ[gid] = make_int4(0, 0, 0, 0);
  if (b < 64) {
    int row = b * 4 + wave;
    u64 sel = pack784_sel(W0 + (size_t)row * 784, 0.0f, lane);
    if (lane < 13) wb0[lane * 256 + row] = sel;
  } else if (b < 128) {
    int row = (b - 64) * 4 + wave;
    u64 sel = pack256_sel(W1 + (size_t)row * 256, lane);
    if (lane < 4) wb1[lane * 256 + row] = sel;
  } else if (b < 192) {
    int row = (b - 128) * 4 + wave;
    u64 sel = pack256_sel(W2 + (size_t)row * 256, lane);
    if (lane < 4) wb2[lane * 256 + row] = sel;
  } else if (b < 256) {
    int row = (b - 192) * 4 + wave;
    u64 sel = pack256_sel(W3 + (size_t)row * 256, lane);
    if (lane < 4) wb3[lane * 256 + row] = sel;
  } else {
    for (int row = wave; row < 10; row += 4) {
      u64 sel = pack256_sel(W4 + (size_t)row * 256, lane);
      if (lane < 4) wb4[lane * 16 + row] = sel;
    }
  }
}

// ---------------- K2: pack x tile -> LDS, layer-0 matmul, h0 + stats0 ----------------
// (256,3): ~170-VGPR cap -- enough for 13 resident weight words + deep
// pack-load pipelining, still 12 waves/CU (x8 blocks co-resident at 2048).
__global__ __launch_bounds__(256, 3) void mm0_kernel(
    const float* __restrict__ x, const u64* __restrict__ wb0T,
    short* __restrict__ h0, int* __restrict__ sumd_rep, u64* __restrict__ sumdd_rep) {
  const int b = blockIdx.x, tid = threadIdx.x;
  const int lane = tid & 63, wave = tid >> 6;
  const int row0 = b * 16;
  __shared__ u64 a0T[16 * 16];
  // 13 named weight registers, loaded once (coalesced), kept live.
  u64 w0  = wb0T[ 0 * 256 + tid], w1  = wb0T[ 1 * 256 + tid];
  u64 w2  = wb0T[ 2 * 256 + tid], w3  = wb0T[ 3 * 256 + tid];
  u64 w4  = wb0T[ 4 * 256 + tid], w5  = wb0T[ 5 * 256 + tid];
  u64 w6  = wb0T[ 6 * 256 + tid], w7  = wb0T[ 7 * 256 + tid];
  u64 w8  = wb0T[ 8 * 256 + tid], w9  = wb0T[ 9 * 256 + tid];
  u64 w10 = wb0T[10 * 256 + tid], w11 = wb0T[11 * 256 + tid];
  u64 w12 = wb0T[12 * 256 + tid];
  // pack: each wave owns 4 consecutive rows
  {
    const float* base = x + (size_t)(row0 + wave * 4) * 784;
#pragma unroll
    for (int it = 0; it < 4; ++it) {
      u64 sel = pack784_sel(base + (size_t)it * 784, 0.5f, lane);
      if (lane < 16) a0T[(wave * 4 + it) * 16 + lane] = sel;  // words 13..15 = 0
    }
  }
  __syncthreads();
  int sd = 0; unsigned sdd = 0;                      // 16*784^2 = 9.8M fits u32
#pragma unroll 4
  for (int r = 0; r < 16; ++r) {
    const u64* ap = &a0T[r * 16];
    int d = __popcll(ap[0] ^ w0)   + __popcll(ap[1] ^ w1)
          + __popcll(ap[2] ^ w2)   + __popcll(ap[3] ^ w3)
          + __popcll(ap[4] ^ w4)   + __popcll(ap[5] ^ w5)
          + __popcll(ap[6] ^ w6)   + __popcll(ap[7] ^ w7)
          + __popcll(ap[8] ^ w8)   + __popcll(ap[9] ^ w9)
          + __popcll(ap[10] ^ w10) + __popcll(ap[11] ^ w11)
          + __popcll(ap[12] ^ w12);
    h0[(size_t)(row0 + r) * 256 + tid] = (short)(784 - 2 * d);
    sd += d; sdd += (unsigned)(d * d);
  }
  const int rep = b & (NREP - 1);
  atomicAdd(&sumd_rep [(rep * 5 + 0) * 256 + tid], sd);
  atomicAdd(&sumdd_rep[(rep * 5 + 0) * 256 + tid], (u64)sdd);
}

// ---------------- K3: binarize BN(h0) -> a1 bits, + layer-1 stats ----------------
__global__ __launch_bounds__(256, 4) void b0_kernel(
    const short* __restrict__ h0,
    int* __restrict__ sumd_rep, u64* __restrict__ sumdd_rep,
    const float* __restrict__ g0, const float* __restrict__ bb0,
    u64* __restrict__ a1, const u64* __restrict__ wb1T) {
  const int b = blockIdx.x, tid = threadIdx.x;
  const int lane = tid & 63, wave = tid >> 6;
  const int row0 = b * 32;
  float gs, md;
  bn_gs_md(sumd_rep, sumdd_rep, 0, tid, g0, gs, md);
  const float mh = 784.0f - 2.0f * md;
  const float bb = bb0[tid];
  u64 wn0 = wb1T[0 * 256 + tid], wn1 = wb1T[1 * 256 + tid];
  u64 wn2 = wb1T[2 * 256 + tid], wn3 = wb1T[3 * 256 + tid];
  __shared__ u64 bits[32 * 4];
#pragma unroll 8
  for (int r = 0; r < 32; ++r) {
    float hv = (float)h0[(size_t)(row0 + r) * 256 + tid];
    bool bit = fmaf(gs, hv - mh, bb) >= 0.0f;
    u64 m = __ballot(bit);
    if (lane == 0) bits[r * 4 + wave] = m;
  }
  __syncthreads();
  if (tid < 128) a1[(size_t)row0 * 4 + tid] = bits[tid];
  int sd = 0; unsigned sdd = 0;     // 32 * 256^2 = 2.1M fits u32
#pragma unroll 8
  for (int r = 0; r < 32; ++r) {
    int d = __popcll(bits[r*4+0] ^ wn0) + __popcll(bits[r*4+1] ^ wn1)
          + __popcll(bits[r*4+2] ^ wn2) + __popcll(bits[r*4+3] ^ wn3);
    sd += d; sdd += (unsigned)(d * d);
  }
  const int rep = b & (NREP - 1);
  atomicAdd(&sumd_rep [(rep * 5 + 1) * 256 + tid], sd);
  atomicAdd(&sumdd_rep[(rep * 5 + 1) * 256 + tid], (u64)sdd);
}

// ---------------- K4..K6: layer k -> a_{k+1} bits + layer-(k+1) stats ----------------
template<int LAYER, int NNEXT, int NSTRIDE>
__global__ __launch_bounds__(256, 4) void bmid_kernel(
    const u64* __restrict__ aK, const u64* __restrict__ wbKT,
    int* __restrict__ sumd_rep, u64* __restrict__ sumdd_rep,
    const float* __restrict__ gK, const float* __restrict__ bK,
    u64* __restrict__ aN, const u64* __restrict__ wbNT) {
  const int b = blockIdx.x, tid = threadIdx.x;
  const int lane = tid & 63, wave = tid >> 6;
  const int row0 = b * 32;
  __shared__ u64 ain[32 * 4];
  __shared__ u64 bits[32 * 4];
  if (tid < 128) ain[tid] = aK[(size_t)row0 * 4 + tid];
  float gs, md;
  bn_gs_md(sumd_rep, sumdd_rep, LAYER, tid, gK, gs, md);
  const float A = -2.0f * gs;
  const float C = fmaf(gs, 2.0f * md, bK[tid]);
  u64 wk0 = wbKT[0 * 256 + tid], wk1 = wbKT[1 * 256 + tid];
  u64 wk2 = wbKT[2 * 256 + tid], wk3 = wbKT[3 * 256 + tid];
  __syncthreads();
#pragma unroll 8
  for (int r = 0; r < 32; ++r) {
    int d = __popcll(ain[r*4+0] ^ wk0) + __popcll(ain[r*4+1] ^ wk1)
          + __popcll(ain[r*4+2] ^ wk2) + __popcll(ain[r*4+3] ^ wk3);
    bool bit = fmaf(A, (float)d, C) >= 0.0f;
    u64 m = __ballot(bit);
    if (lane == 0) bits[r * 4 + wave] = m;
  }
  __syncthreads();
  if (tid < 128) aN[(size_t)row0 * 4 + tid] = bits[tid];
  if (tid < NNEXT) {
    u64 wn0 = wbNT[0 * NSTRIDE + tid], wn1 = wbNT[1 * NSTRIDE + tid];
    u64 wn2 = wbNT[2 * NSTRIDE + tid], wn3 = wbNT[3 * NSTRIDE + tid];
    int sd = 0; unsigned sdd = 0;
#pragma unroll 8
    for (int r = 0; r < 32; ++r) {
      int d = __popcll(bits[r*4+0] ^ wn0) + __popcll(bits[r*4+1] ^ wn1)
            + __popcll(bits[r*4+2] ^ wn2) + __popcll(bits[r*4+3] ^ wn3);
      sd += d; sdd += (unsigned)(d * d);
    }
    const int rep = b & (NREP - 1);
    atomicAdd(&sumd_rep [(rep * 5 + LAYER + 1) * 256 + tid], sd);
    atomicAdd(&sumdd_rep[(rep * 5 + LAYER + 1) * 256 + tid], (u64)sdd);
  }
}

// ---------------- K7: layer 4 + BN + softmax ----------------
__global__ __launch_bounds__(256) void b4_kernel(
    const u64* __restrict__ a4, const u64* __restrict__ wb4T,
    const int* __restrict__ sumd_rep, const u64* __restrict__ sumdd_rep,
    const float* __restrict__ g4, const float* __restrict__ bb4,
    float* __restrict__ out) {
  __shared__ float sA[10], sC[10];
  __shared__ u64 w4s[40];
  const int tid = threadIdx.x;
  if (tid < 40) w4s[tid] = wb4T[(tid & 3) * 16 + (tid >> 2)];  // [c*4+i] = word i of class c
  if (tid < 10) {
    float gs, md;
    bn_gs_md(sumd_rep, sumdd_rep, 4, tid, g4, gs, md);
    sA[tid] = -2.0f * gs;
    sC[tid] = fmaf(gs, 2.0f * md, bb4[tid]);
  }
  __syncthreads();
  const int row = blockIdx.x * 256 + tid;
  u64 a[4];
#pragma unroll
  for (int i = 0; i < 4; ++i) a[i] = a4[(size_t)row * 4 + i];
  float y[10];
  float mx = -1e30f;
#pragma unroll
  for (int c = 0; c < 10; ++c) {
    int d = __popcll(a[0] ^ w4s[c*4+0]) + __popcll(a[1] ^ w4s[c*4+1])
          + __popcll(a[2] ^ w4s[c*4+2]) + __popcll(a[3] ^ w4s[c*4+3]);
    y[c] = fmaf(sA[c], (float)d, sC[c]);
    mx = fmaxf(mx, y[c]);
  }
  float sum = 0.0f;
#pragma unroll
  for (int c = 0; c < 10; ++c) { y[c] = __expf(y[c] - mx); sum += y[c]; }
  float inv = 1.0f / sum;
#pragma unroll
  for (int c = 0; c < 10; ++c) out[(size_t)row * 10 + c] = y[c] * inv;
}

// ---------------- host ----------------
extern "C" void kernel_launch(void* const* d_in, const int* in_sizes, int n_in,
                              void* d_out, int out_size, void* d_ws, size_t ws_size,
                              hipStream_t stream) {
  (void)in_sizes; (void)n_in; (void)out_size; (void)ws_size;
  const float* x   = (const float*)d_in[0];
  const float* W0  = (const float*)d_in[1];
  const float* g0  = (const float*)d_in[2];
  const float* bb0 = (const float*)d_in[3];
  const float* W1  = (const float*)d_in[4];
  const float* g1  = (const float*)d_in[5];
  const float* bb1 = (const float*)d_in[6];
  const float* W2  = (const float*)d_in[7];
  const float* g2  = (const float*)d_in[8];
  const float* bb2 = (const float*)d_in[9];
  const float* W3  = (const float*)d_in[10];
  const float* g3  = (const float*)d_in[11];
  const float* bb3 = (const float*)d_in[12];
  const float* W4  = (const float*)d_in[13];
  const float* g4  = (const float*)d_in[14];
  const float* bb4 = (const float*)d_in[15];

  char* ws = (char*)d_ws;
  u64*   wb0 = (u64*)(ws + OFF_WB0);
  u64*   wb1 = (u64*)(ws + OFF_WB1);
  u64*   wb2 = (u64*)(ws + OFF_WB2);
  u64*   wb3 = (u64*)(ws + OFF_WB3);
  u64*   wb4 = (u64*)(ws + OFF_WB4);
  int*   sumd  = (int*)(ws + OFF_SUMD);
  u64*   sumdd = (u64*)(ws + OFF_SUMDD);
  u64*   a1 = (u64*)(ws + OFF_A1);
  u64*   a2 = (u64*)(ws + OFF_A2);
  u64*   a3 = (u64*)(ws + OFF_A3);
  u64*   a4 = (u64*)(ws + OFF_A4);
  short* h0 = (short*)(ws + OFF_H0);

  pack_weights<<<257, 256, 0, stream>>>(W0, W1, W2, W3, W4,
                                        wb0, wb1, wb2, wb3, wb4,
                                        (int4*)(ws + OFF_SUMD));
  mm0_kernel<<<2048, 256, 0, stream>>>(x, wb0, h0, sumd, sumdd);
  b0_kernel<<<1024, 256, 0, stream>>>(h0, sumd, sumdd, g0, bb0, a1, wb1);
  bmid_kernel<1, 256, 256><<<1024, 256, 0, stream>>>(a1, wb1, sumd, sumdd, g1, bb1, a2, wb2);
  bmid_kernel<2, 256, 256><<<1024, 256, 0, stream>>>(a2, wb2, sumd, sumdd, g2, bb2, a3, wb3);
  bmid_kernel<3, 10, 16><<<1024, 256, 0, stream>>>(a3, wb3, sumd, sumdd, g3, bb3, a4, wb4);
  b4_kernel<<<128, 256, 0, stream>>>(a4, wb4, sumd, sumdd, g4, bb4, (float*)d_out);
}